// Round 16
// baseline (307.430 us; speedup 1.0000x reference)
//
#include <hip/hip_runtime.h>
#include <hip/hip_bf16.h>

typedef unsigned short u16t;
typedef short bf16x8 __attribute__((ext_vector_type(8)));
typedef short bf16x4 __attribute__((ext_vector_type(4)));
typedef float f32x4 __attribute__((ext_vector_type(4)));

#define T_SEQ 4096
#define NH    12
#define HD    64
#define C3    2304
#define CDIM  768
#define STRIP_KV 512
#define SLOTS 144         // sum over qt=0..31 of ceil((qt+1)/4)
#define SC_F  0.18033688011112042f   // (1/sqrt(64)) * log2(e), folded into Q

__device__ __forceinline__ float bf2f(u16t u) {
  union { unsigned int i; float f; } c; c.i = ((unsigned int)u) << 16; return c.f;
}
__device__ __forceinline__ u16t f2bf(float f) {
  union { float f; unsigned int i; } c; c.f = f;
  unsigned int u = c.i;
  u += 0x7fffu + ((u >> 16) & 1u);   // RNE
  return (u16t)(u >> 16);
}
// Packed f32x2 -> bf16x2 (v_cvt_pk_bf16_f32 on gfx950); low 16 bits = a.
__device__ __forceinline__ unsigned pk2bf(float a, float b) {
  __hip_bfloat162 h = __float22bfloat162_rn(make_float2(a, b));
  union { __hip_bfloat162 h; unsigned u; } c; c.h = h; return c.u;
}

// LDS-only barrier: in-flight global->VGPR prefetch stays outstanding
// (unlike __syncthreads, which emits s_waitcnt vmcnt(0) and serializes the
// staging loads with compute -- the m97-plateau stall).
#define BARRIER_LGKM() __asm__ __volatile__("s_waitcnt lgkmcnt(0)\n\ts_barrier" ::: "memory")

// ---------------------------------------------------------------------------
// Both weight transposes in ONE launch: z=0 -> Wqkv, z=1 -> Wproj.
// Inputs are fp32 (hard evidence: R1's bf16 interpretation produced NaN).
// ---------------------------------------------------------------------------
__global__ __launch_bounds__(256) void transpose_weights(const float* __restrict__ Wqkv,
                                                         const float* __restrict__ Wproj,
                                                         u16t* __restrict__ WqkvT,
                                                         u16t* __restrict__ WprojT) {
  __shared__ u16t tile[32][33];
  const int z = blockIdx.z;
  const int Cc = z ? CDIM : C3;
  if (z && blockIdx.x >= (unsigned)(CDIM / 32)) return;
  const float* in = z ? Wproj : Wqkv;
  u16t* out = z ? WprojT : WqkvT;
  const int tx = threadIdx.x, ty = threadIdx.y;       // block (32,8)
  const int c0 = blockIdx.x * 32, r0 = blockIdx.y * 32;
#pragma unroll
  for (int i = 0; i < 32; i += 8)
    tile[ty + i][tx] = f2bf(in[(size_t)(r0 + ty + i) * Cc + c0 + tx]);
  __syncthreads();
#pragma unroll
  for (int i = 0; i < 32; i += 8)
    out[(size_t)(c0 + ty + i) * CDIM + r0 + tx] = tile[tx][ty + i];
}

// ---------------------------------------------------------------------------
// C[M,N] = A[M,K]*B[K,N] + bias[N]; Bt row-major [N][K] bf16.
// Tile MT x (32*NF), BK=32, 256 threads.  R16: register-carried prefetch +
// LGKM-only barriers (the verified attn staging pattern) -- tile k+1's
// global loads stay in flight across tile k's MFMA; ds_writes run after
// compute.  AF32: A is fp32 and is packed to bf16 in-register during the
// ds_write (folds the x->bf16 convert kernel into gemm1 for free).
// Columns < qcols are scaled by qscale post-bias (softmax scale into Q).
// ---------------------------------------------------------------------------
template <int MT, int NF, bool AF32, bool OUTF32>
__global__ __launch_bounds__(256) void gemm_bt_bias(
    const void* __restrict__ Ain, const u16t* __restrict__ Bt,
    const float* __restrict__ bias, void* __restrict__ Cout,
    int M, int N, int K, int qcols, float qscale) {
  constexpr int BN = 32 * NF;
  constexpr int MI = MT / 32;          // M fragments per wave
  constexpr int AR = MT / 64;          // A staging rounds (16B chunk each)
  constexpr int BR = NF / 2;           // B staging rounds
  __shared__ u16t lA[MT * 32];
  __shared__ u16t lB[BN * 32];
  const int t = threadIdx.x;
  const int lane = t & 63;
  const int wid  = t >> 6;
  const int quad = lane >> 4, l16 = lane & 15;
  const int m0 = blockIdx.y * MT, n0 = blockIdx.x * BN;
  const int wm = (wid >> 1) * (16 * MI), wn = (wid & 1) * (16 * NF);

  f32x4 acc[MI][NF];
#pragma unroll
  for (int i = 0; i < MI; ++i)
#pragma unroll
    for (int j = 0; j < NF; ++j) acc[i][j] = (f32x4){0.f, 0.f, 0.f, 0.f};

  // prefetch registers (AF32 needs 2 uint4 per A chunk: 8 floats)
  uint4 pa[AR * 2], pb[BR];

#define GLOADK(K0)                                                            \
  do {                                                                        \
    _Pragma("unroll")                                                         \
    for (int rd = 0; rd < AR; ++rd) {                                         \
      const int e = rd * 256 + t;                                             \
      const int row = m0 + (e >> 2), col = (K0) + (e & 3) * 8;                \
      if (AF32) {                                                             \
        const float* ap = (const float*)Ain + (size_t)row * K + col;          \
        pa[rd * 2]     = *(const uint4*)ap;                                   \
        pa[rd * 2 + 1] = *(const uint4*)(ap + 4);                             \
      } else {                                                                \
        pa[rd * 2] = *(const uint4*)((const u16t*)Ain + (size_t)row * K + col); \
      }                                                                       \
    }                                                                         \
    _Pragma("unroll")                                                         \
    for (int rd = 0; rd < BR; ++rd) {                                         \
      const int e = rd * 256 + t;                                             \
      pb[rd] = *(const uint4*)(Bt + (size_t)(n0 + (e >> 2)) * K + (K0) + (e & 3) * 8); \
    }                                                                         \
  } while (0)

#define STOREK()                                                              \
  do {                                                                        \
    _Pragma("unroll")                                                         \
    for (int rd = 0; rd < AR; ++rd) {                                         \
      const int e = rd * 256 + t;                                             \
      if (AF32) {                                                             \
        union { uint4 u; float f[4]; } a0, a1;                                \
        a0.u = pa[rd * 2]; a1.u = pa[rd * 2 + 1];                             \
        union { uint4 u; unsigned w[4]; } o;                                  \
        o.w[0] = pk2bf(a0.f[0], a0.f[1]); o.w[1] = pk2bf(a0.f[2], a0.f[3]);   \
        o.w[2] = pk2bf(a1.f[0], a1.f[1]); o.w[3] = pk2bf(a1.f[2], a1.f[3]);   \
        *(uint4*)&lA[e * 8] = o.u;                                            \
      } else {                                                                \
        *(uint4*)&lA[e * 8] = pa[rd * 2];                                     \
      }                                                                       \
    }                                                                         \
    _Pragma("unroll")                                                         \
    for (int rd = 0; rd < BR; ++rd)                                           \
      *(uint4*)&lB[(rd * 256 + t) * 8] = pb[rd];                              \
  } while (0)

  GLOADK(0);
  STOREK();

  for (int k0 = 0; k0 < K; k0 += 32) {
    const bool hn = (k0 + 32 < K);
    if (hn) GLOADK(k0 + 32);           // stays in flight across compute
    BARRIER_LGKM();                    // publish tile k0 (LDS only)
    bf16x8 af[MI], bfr[NF];
#pragma unroll
    for (int i = 0; i < MI; ++i)
      af[i] = *(const bf16x8*)&lA[(wm + i * 16 + l16) * 32 + quad * 8];
#pragma unroll
    for (int i = 0; i < NF; ++i)
      bfr[i] = *(const bf16x8*)&lB[(wn + i * 16 + l16) * 32 + quad * 8];
#pragma unroll
    for (int i = 0; i < MI; ++i)
#pragma unroll
      for (int j = 0; j < NF; ++j)
        acc[i][j] = __builtin_amdgcn_mfma_f32_16x16x32_bf16(af[i], bfr[j], acc[i][j], 0, 0, 0);
    BARRIER_LGKM();                    // all reads of tile k0 done
    if (hn) STOREK();                  // overwrite with tile k0+32
  }

#pragma unroll
  for (int j = 0; j < NF; ++j) {
    const int col = n0 + wn + j * 16 + l16;
    const float bv = bias[col];
    const float cs = (col < qcols) ? qscale : 1.0f;
#pragma unroll
    for (int i = 0; i < MI; ++i) {
      const int rowb = m0 + wm + i * 16 + quad * 4;
#pragma unroll
      for (int r = 0; r < 4; ++r) {
        const float val = (acc[i][j][r] + bv) * cs;
        const size_t idx = (size_t)(rowb + r) * N + col;
        if (OUTF32) ((float*)Cout)[idx] = val;
        else        ((u16t*)Cout)[idx] = f2bf(val);
      }
    }
  }
#undef GLOADK
#undef STOREK
}

// ---------------------------------------------------------------------------
// Split-KV causal attention (R15 best: P-in-registers, XCD-balanced grid,
// VALU diet, launch_bounds(256,4) -- 69 us, no spill).  Unchanged.
// ---------------------------------------------------------------------------
#define KSTR 88
#define VSTR 88

__global__ __launch_bounds__(256, 4) void attn_partial(const u16t* __restrict__ qkv,
                                                       u16t* __restrict__ pO,
                                                       float* __restrict__ pL) {
  const int h     = blockIdx.x;
  const int strip = blockIdx.y;
  const int qt    = 31 - (int)blockIdx.z;           // heavy q-tiles first
  const int q0 = qt * 128;
  const int kv_begin = strip * STRIP_KV;
  const int kv_end   = q0 + 128;
  if (kv_begin >= kv_end) return;                   // strip above diagonal
  const int kv_stop = (kv_begin + STRIP_KV < kv_end) ? kv_begin + STRIP_KV : kv_end;
  const int a = qt >> 2, b = qt & 3;
  const int slot = (a + 1) * (2 * a + b) + strip;

  __shared__ u16t lK[64 * KSTR];        // [kv][d]
  __shared__ u16t lVt[64 * VSTR];       // [d][kv^swz] (reused as epilogue scratch)

  const int t = threadIdx.x;
  const int lane = t & 63;
  const int wid  = t >> 6;
  const int quad = lane >> 4, l16 = lane & 15;
  const int wr = q0 + wid * 32;                     // wave owns 32 q rows

  const int krow = t >> 3, kcol = (t & 7) * 8;
  const int vk0 = 4 * (t >> 4);
  const int vd0 = 4 * (t & 15);
  const int vswz = (t & 3) << 3;
  const u16t* Kbase = qkv + CDIM + h * HD;
  const u16t* Vbase = qkv + 2 * CDIM + h * HD;

  // Q fragments (pre-scaled by SC in gemm1's epilogue)
  bf16x8 qf[2][2];
#pragma unroll
  for (int qn = 0; qn < 2; ++qn) {
    const int row = wr + qn * 16 + l16;
#pragma unroll
    for (int kd = 0; kd < 2; ++kd)
      qf[qn][kd] = *(const bf16x8*)(qkv + (size_t)row * C3 + h * HD + kd * 32 + quad * 8);
  }

  f32x4 oaccT[4][2];                 // O^T tiles: [dn][qn], row=d, col=q
  f32x4 laccT[2];                    // l via ones-MFMA (all 4 regs identical)
#pragma unroll
  for (int dn = 0; dn < 4; ++dn)
#pragma unroll
    for (int qn = 0; qn < 2; ++qn) oaccT[dn][qn] = (f32x4){0.f, 0.f, 0.f, 0.f};
#pragma unroll
  for (int qn = 0; qn < 2; ++qn) laccT[qn] = (f32x4){0.f, 0.f, 0.f, 0.f};
  bf16x4 ones4;
#pragma unroll
  for (int i = 0; i < 4; ++i) ones4[i] = (short)0x3F80;  // bf16 1.0

  const int pswz = ((l16 >> 2) & 3) << 3;          // V read-side swizzle key

  uint4 kreg0, kreg1;
  union { uint2 u; u16t hw[4]; } vreg[4];

#define LOAD_TILE(KV0)                                                        \
  do {                                                                        \
    kreg0 = *(const uint4*)(Kbase + (size_t)((KV0) + krow) * C3 + kcol);      \
    kreg1 = *(const uint4*)(Kbase + (size_t)((KV0) + krow + 32) * C3 + kcol); \
    _Pragma("unroll")                                                         \
    for (int i = 0; i < 4; ++i)                                               \
      vreg[i].u = *(const uint2*)(Vbase + (size_t)((KV0) + vk0 + i) * C3 + vd0); \
  } while (0)

#define STORE_TILE()                                                          \
  do {                                                                        \
    *(uint4*)&lK[krow * KSTR + kcol] = kreg0;                                 \
    *(uint4*)&lK[(krow + 32) * KSTR + kcol] = kreg1;                          \
    _Pragma("unroll")                                                         \
    for (int j = 0; j < 4; ++j) {                                             \
      union { uint2 u; u16t hw[4]; } w;                                       \
      w.hw[0] = vreg[0].hw[j]; w.hw[1] = vreg[1].hw[j];                       \
      w.hw[2] = vreg[2].hw[j]; w.hw[3] = vreg[3].hw[j];                       \
      *(uint2*)&lVt[(vd0 + j) * VSTR + (vk0 ^ vswz)] = w.u;                   \
    }                                                                         \
  } while (0)

  LOAD_TILE(kv_begin);
  STORE_TILE();

  for (int kv0 = kv_begin; kv0 < kv_stop; kv0 += 64) {
    const bool havenext = (kv0 + 64 < kv_stop);
    if (havenext) LOAD_TILE(kv0 + 64);   // stays in flight across compute
    BARRIER_LGKM();

    if (kv0 <= wr + 31) {                // wave-uniform skip of masked tiles
      // ---- S^T = K · Q^T (Q pre-scaled; exp2 arg is ready) ----
      f32x4 sacc[4][2];                  // [kvt][qn]
#pragma unroll
      for (int kvt = 0; kvt < 4; ++kvt) {
        bf16x8 kf0 = *(const bf16x8*)&lK[(kvt * 16 + l16) * KSTR + quad * 8];
        bf16x8 kf1 = *(const bf16x8*)&lK[(kvt * 16 + l16) * KSTR + 32 + quad * 8];
#pragma unroll
        for (int qn = 0; qn < 2; ++qn) {
          f32x4 s = (f32x4){0.f, 0.f, 0.f, 0.f};
          s = __builtin_amdgcn_mfma_f32_16x16x32_bf16(kf0, qf[qn][0], s, 0, 0, 0);
          s = __builtin_amdgcn_mfma_f32_16x16x32_bf16(kf1, qf[qn][1], s, 0, 0, 0);
          sacc[kvt][qn] = s;
        }
      }
      const bool need_mask = (kv0 + 63 > wr);
      // ---- P^T = exp2(S^T) -> packed bf16 B-operand registers ----
      bf16x4 pbf[4][2];
#pragma unroll
      for (int kvt = 0; kvt < 4; ++kvt)
#pragma unroll
        for (int qn = 0; qn < 2; ++qn) {
          const int qg = wr + qn * 16 + l16;
          float pv[4];
#pragma unroll
          for (int r = 0; r < 4; ++r) {
            const int kvg = kv0 + kvt * 16 + quad * 4 + r;
            float p = __builtin_amdgcn_exp2f(sacc[kvt][qn][r]);
            if (need_mask && (kvg > qg)) p = 0.f;
            pv[r] = p;
          }
          union { bf16x4 v; unsigned u[2]; } pw;
          pw.u[0] = pk2bf(pv[0], pv[1]);
          pw.u[1] = pk2bf(pv[2], pv[3]);
          pbf[kvt][qn] = pw.v;
        }
      // ---- O^T += V^T · P^T ; l += ones · P^T (both pure MFMA) ----
#pragma unroll
      for (int kvt = 0; kvt < 4; ++kvt) {
        const int kvcol = (kvt * 16 + quad * 4) ^ pswz;
#pragma unroll
        for (int qn = 0; qn < 2; ++qn)
          laccT[qn] = __builtin_amdgcn_mfma_f32_16x16x16bf16_1k(
              ones4, pbf[kvt][qn], laccT[qn], 0, 0, 0);
#pragma unroll
        for (int dn = 0; dn < 4; ++dn) {
          bf16x4 vf = *(const bf16x4*)&lVt[(dn * 16 + l16) * VSTR + kvcol];
#pragma unroll
          for (int qn = 0; qn < 2; ++qn)
            oaccT[dn][qn] = __builtin_amdgcn_mfma_f32_16x16x16bf16_1k(
                vf, pbf[kvt][qn], oaccT[dn][qn], 0, 0, 0);
        }
      }
    }
    BARRIER_LGKM();                      // all reads of LDS tile kv0 done
    if (havenext) STORE_TILE();
  }

  // ---- epilogue: O^T -> [q][d] via per-wave LDS transpose; packed converts.
  {
    u16t* scr = &lVt[wid * 16 * 80];     // 16 q-rows x stride 80 per wave
    u16t* po = pO + ((size_t)h * SLOTS + slot) * 128 * HD;
    float* pl = pL + ((size_t)h * SLOTS + slot) * 128;
#pragma unroll
    for (int qn = 0; qn < 2; ++qn) {
#pragma unroll
      for (int dn = 0; dn < 4; ++dn) {
        union { bf16x4 v; unsigned u[2]; } w;
        w.u[0] = pk2bf(oaccT[dn][qn][0], oaccT[dn][qn][1]);
        w.u[1] = pk2bf(oaccT[dn][qn][2], oaccT[dn][qn][3]);
        *(bf16x4*)&scr[l16 * 80 + dn * 16 + quad * 4] = w.v;
      }
      __asm__ __volatile__("s_waitcnt lgkmcnt(0)" ::: "memory");
      const int ql = wid * 32 + qn * 16 + l16;
      uint4 w0 = *(const uint4*)&scr[l16 * 80 + quad * 16];
      uint4 w1 = *(const uint4*)&scr[l16 * 80 + quad * 16 + 8];
      u16t* dst = po + (size_t)ql * HD + quad * 16;
      *(uint4*)dst = w0;
      *(uint4*)(dst + 8) = w1;
      if (quad == 0) pl[ql] = laccT[qn][0];
      __asm__ __volatile__("s_waitcnt lgkmcnt(0)" ::: "memory");
    }
  }
#undef LOAD_TILE
#undef STORE_TILE
}

// ---------------------------------------------------------------------------
// 8-wide: each thread normalizes 8 consecutive d of one (q,h).
// ---------------------------------------------------------------------------
__global__ __launch_bounds__(256) void attn_normalize(const u16t* __restrict__ pO,
                                                      const float* __restrict__ pL,
                                                      u16t* __restrict__ y) {
  const int i = blockIdx.x * 256 + threadIdx.x;   // over T*C/8
  const int q = i / (CDIM / 8), c8 = (i % (CDIM / 8)) * 8;
  const int h = c8 >> 6, d = c8 & 63;
  const int qt = q >> 7, ql = q & 127;
  const int a = qt >> 2, b = qt & 3;
  const int base = (a + 1) * (2 * a + b);
  const int ns = a + 1;                            // ceil((qt+1)/4)
  float o[8] = {0.f, 0.f, 0.f, 0.f, 0.f, 0.f, 0.f, 0.f};
  float l = 0.f;
  for (int s = 0; s < ns; ++s) {
    const size_t sl = (size_t)h * SLOTS + base + s;
    union { uint4 u; u16t hw[8]; } v;
    v.u = *(const uint4*)&pO[(sl * 128 + ql) * HD + d];
#pragma unroll
    for (int j = 0; j < 8; ++j) o[j] += bf2f(v.hw[j]);
    l += pL[sl * 128 + ql];
  }
  const float rl = 1.0f / l;
  union { uint4 u; unsigned w[4]; } wv;
#pragma unroll
  for (int j = 0; j < 4; ++j)
    wv.w[j] = pk2bf(o[2 * j] * rl, o[2 * j + 1] * rl);
  *(uint4*)&y[(size_t)q * CDIM + c8] = wv.u;
}

// ---------------------------------------------------------------------------
extern "C" void kernel_launch(void* const* d_in, const int* in_sizes, int n_in,
                              void* d_out, int out_size, void* d_ws, size_t ws_size,
                              hipStream_t stream) {
  const float* x     = (const float*)d_in[0];
  // d_in[1] = mask (unused — causal mask applied analytically)
  const float* Wqkv  = (const float*)d_in[2];
  const float* bqkv  = (const float*)d_in[3];
  const float* Wproj = (const float*)d_in[4];
  const float* bproj = (const float*)d_in[5];

  u16t* qkv    = (u16t*)d_ws;                     // [4096][2304] bf16
  u16t* ybuf   = qkv    + (size_t)T_SEQ * C3;     // [4096][768]  bf16 (attn out)
  u16t* WqkvT  = ybuf   + (size_t)T_SEQ * CDIM;   // [2304][768]  bf16
  u16t* WprojT = WqkvT  + (size_t)C3 * CDIM;      // [768][768]   bf16
  u16t* pO     = WprojT + (size_t)CDIM * CDIM;    // [12][144][128][64] bf16
  float* pL    = (float*)(pO + (size_t)NH * SLOTS * 128 * HD);  // [12][144][128] f32

  transpose_weights<<<dim3(C3 / 32, CDIM / 32, 2), dim3(32, 8), 0, stream>>>(
      Wqkv, Wproj, WqkvT, WprojT);
  gemm_bt_bias<128, 4, true, false><<<dim3(C3 / 128, T_SEQ / 128), 256, 0, stream>>>(
      x, WqkvT, bqkv, qkv, T_SEQ, C3, CDIM, CDIM, SC_F);
  attn_partial<<<dim3(NH, 8, T_SEQ / 128), 256, 0, stream>>>(qkv, pO, pL);
  attn_normalize<<<(T_SEQ * CDIM / 8) / 256, 256, 0, stream>>>(pO, pL, ybuf);
  gemm_bt_bias<64, 2, false, true><<<dim3(CDIM / 64, T_SEQ / 64), 256, 0, stream>>>(
      ybuf, WprojT, bproj, d_out, T_SEQ, CDIM, CDIM, 0, 1.0f);
}

// Round 17
// 226.634 us; speedup vs baseline: 1.3565x; 1.3565x over previous
//
#include <hip/hip_runtime.h>
#include <hip/hip_bf16.h>

typedef unsigned short u16t;
typedef short bf16x8 __attribute__((ext_vector_type(8)));
typedef short bf16x4 __attribute__((ext_vector_type(4)));
typedef float f32x4 __attribute__((ext_vector_type(4)));

#define T_SEQ 4096
#define NH    12
#define HD    64
#define C3    2304
#define CDIM  768
#define STRIP_KV 512
#define SLOTS 144         // sum over qt=0..31 of ceil((qt+1)/4)
#define SC_F  0.18033688011112042f   // (1/sqrt(64)) * log2(e), folded into Q

__device__ __forceinline__ float bf2f(u16t u) {
  union { unsigned int i; float f; } c; c.i = ((unsigned int)u) << 16; return c.f;
}
__device__ __forceinline__ u16t f2bf(float f) {
  union { float f; unsigned int i; } c; c.f = f;
  unsigned int u = c.i;
  u += 0x7fffu + ((u >> 16) & 1u);   // RNE
  return (u16t)(u >> 16);
}
// Packed f32x2 -> bf16x2 (v_cvt_pk_bf16_f32 on gfx950); low 16 bits = a.
__device__ __forceinline__ unsigned pk2bf(float a, float b) {
  __hip_bfloat162 h = __float22bfloat162_rn(make_float2(a, b));
  union { __hip_bfloat162 h; unsigned u; } c; c.h = h; return c.u;
}
__device__ __forceinline__ void gload16(const u16t* g, u16t* l) {
  __builtin_amdgcn_global_load_lds((const __attribute__((address_space(1))) void*)g,
                                   (__attribute__((address_space(3))) void*)l,
                                   16, 0, 0);
}

// LDS-only barrier (attn only): in-flight global->VGPR prefetch stays
// outstanding.  NOT used in the GEMMs -- global_load_lds staging needs the
// full __syncthreads vmcnt drain, and the m97 ladder shows global_load_lds
// beats register round-trip staging for GEMM (874 vs 517 TF; R16 re-proved
// it the hard way: register-staged gemm1 ran 93 us vs <55 us).
#define BARRIER_LGKM() __asm__ __volatile__("s_waitcnt lgkmcnt(0)\n\ts_barrier" ::: "memory")

// ---------------------------------------------------------------------------
// Inputs are fp32 (hard evidence: R1's bf16 interpretation produced NaN).
// ---------------------------------------------------------------------------
__global__ __launch_bounds__(256) void convert_to_bf16(const float* __restrict__ in,
                                                       u16t* __restrict__ out, int n) {
  int i = blockIdx.x * 256 + threadIdx.x;
  const int stride = gridDim.x * 256;
  for (; i < n; i += stride) out[i] = f2bf(in[i]);
}

// Both weight transposes in ONE launch: z=0 -> Wqkv, z=1 -> Wproj.
__global__ __launch_bounds__(256) void transpose_weights(const float* __restrict__ Wqkv,
                                                         const float* __restrict__ Wproj,
                                                         u16t* __restrict__ WqkvT,
                                                         u16t* __restrict__ WprojT) {
  __shared__ u16t tile[32][33];
  const int z = blockIdx.z;
  const int Cc = z ? CDIM : C3;
  if (z && blockIdx.x >= (unsigned)(CDIM / 32)) return;
  const float* in = z ? Wproj : Wqkv;
  u16t* out = z ? WprojT : WqkvT;
  const int tx = threadIdx.x, ty = threadIdx.y;       // block (32,8)
  const int c0 = blockIdx.x * 32, r0 = blockIdx.y * 32;
#pragma unroll
  for (int i = 0; i < 32; i += 8)
    tile[ty + i][tx] = f2bf(in[(size_t)(r0 + ty + i) * Cc + c0 + tx]);
  __syncthreads();
#pragma unroll
  for (int i = 0; i < 32; i += 8)
    out[(size_t)(c0 + ty + i) * CDIM + r0 + tx] = tile[tx][ty + i];
}

// ---------------------------------------------------------------------------
// C[M,N] = A[M,K]*B[K,N] + bias[N]; A,Bt bf16 (Bt row-major [N][K]).
// Tile MT x (32*NF), BK=32, 256 threads, global_load_lds staging (the
// verified-fast m97 pattern).  Columns < qcols scaled by qscale post-bias.
// ---------------------------------------------------------------------------
template <int MT, int NF, bool OUTF32>
__global__ __launch_bounds__(256) void gemm_bt_bias(
    const u16t* __restrict__ A, const u16t* __restrict__ Bt,
    const float* __restrict__ bias, void* __restrict__ Cout,
    int M, int N, int K, int qcols, float qscale) {
  constexpr int BN = 32 * NF;
  constexpr int MI = MT / 32;          // M fragments per wave
  __shared__ u16t lA[MT * 32];
  __shared__ u16t lB[BN * 32];
  const int t = threadIdx.x;
  const int lane = t & 63;
  const int wid  = t >> 6;
  const int quad = lane >> 4, l16 = lane & 15;
  const int m0 = blockIdx.y * MT, n0 = blockIdx.x * BN;
  const int wm = (wid >> 1) * (16 * MI), wn = (wid & 1) * (16 * NF);

  f32x4 acc[MI][NF];
#pragma unroll
  for (int i = 0; i < MI; ++i)
#pragma unroll
    for (int j = 0; j < NF; ++j) acc[i][j] = (f32x4){0.f, 0.f, 0.f, 0.f};

  for (int k0 = 0; k0 < K; k0 += 32) {
    {
#pragma unroll
      for (int rd = 0; rd < MT / 64; ++rd) {
        const int e = rd * 256 + t;
        gload16(A + (size_t)(m0 + (e >> 2)) * K + k0 + (e & 3) * 8, &lA[e * 8]);
      }
#pragma unroll
      for (int rd = 0; rd < NF / 2; ++rd) {
        const int e = rd * 256 + t;
        gload16(Bt + (size_t)(n0 + (e >> 2)) * K + k0 + (e & 3) * 8, &lB[e * 8]);
      }
    }
    __syncthreads();
    bf16x8 af[MI], bfr[NF];
#pragma unroll
    for (int i = 0; i < MI; ++i)
      af[i] = *(const bf16x8*)&lA[(wm + i * 16 + l16) * 32 + quad * 8];
#pragma unroll
    for (int i = 0; i < NF; ++i)
      bfr[i] = *(const bf16x8*)&lB[(wn + i * 16 + l16) * 32 + quad * 8];
#pragma unroll
    for (int i = 0; i < MI; ++i)
#pragma unroll
      for (int j = 0; j < NF; ++j)
        acc[i][j] = __builtin_amdgcn_mfma_f32_16x16x32_bf16(af[i], bfr[j], acc[i][j], 0, 0, 0);
    __syncthreads();
  }

#pragma unroll
  for (int j = 0; j < NF; ++j) {
    const int col = n0 + wn + j * 16 + l16;
    const float bv = bias[col];
    const float cs = (col < qcols) ? qscale : 1.0f;
#pragma unroll
    for (int i = 0; i < MI; ++i) {
      const int rowb = m0 + wm + i * 16 + quad * 4;
#pragma unroll
      for (int r = 0; r < 4; ++r) {
        const float val = (acc[i][j][r] + bv) * cs;
        const size_t idx = (size_t)(rowb + r) * N + col;
        if (OUTF32) ((float*)Cout)[idx] = val;
        else        ((u16t*)Cout)[idx] = f2bf(val);
      }
    }
  }
}

// ---------------------------------------------------------------------------
// Split-KV causal attention (R15 best: P-in-registers, XCD-balanced grid,
// VALU diet, launch_bounds(256,4) -- 69 us, no spill).  Unchanged.
// ---------------------------------------------------------------------------
#define KSTR 88
#define VSTR 88

__global__ __launch_bounds__(256, 4) void attn_partial(const u16t* __restrict__ qkv,
                                                       u16t* __restrict__ pO,
                                                       float* __restrict__ pL) {
  const int h     = blockIdx.x;
  const int strip = blockIdx.y;
  const int qt    = 31 - (int)blockIdx.z;           // heavy q-tiles first
  const int q0 = qt * 128;
  const int kv_begin = strip * STRIP_KV;
  const int kv_end   = q0 + 128;
  if (kv_begin >= kv_end) return;                   // strip above diagonal
  const int kv_stop = (kv_begin + STRIP_KV < kv_end) ? kv_begin + STRIP_KV : kv_end;
  const int a = qt >> 2, b = qt & 3;
  const int slot = (a + 1) * (2 * a + b) + strip;

  __shared__ u16t lK[64 * KSTR];        // [kv][d]
  __shared__ u16t lVt[64 * VSTR];       // [d][kv^swz] (reused as epilogue scratch)

  const int t = threadIdx.x;
  const int lane = t & 63;
  const int wid  = t >> 6;
  const int quad = lane >> 4, l16 = lane & 15;
  const int wr = q0 + wid * 32;                     // wave owns 32 q rows

  const int krow = t >> 3, kcol = (t & 7) * 8;
  const int vk0 = 4 * (t >> 4);
  const int vd0 = 4 * (t & 15);
  const int vswz = (t & 3) << 3;
  const u16t* Kbase = qkv + CDIM + h * HD;
  const u16t* Vbase = qkv + 2 * CDIM + h * HD;

  // Q fragments (pre-scaled by SC in gemm1's epilogue)
  bf16x8 qf[2][2];
#pragma unroll
  for (int qn = 0; qn < 2; ++qn) {
    const int row = wr + qn * 16 + l16;
#pragma unroll
    for (int kd = 0; kd < 2; ++kd)
      qf[qn][kd] = *(const bf16x8*)(qkv + (size_t)row * C3 + h * HD + kd * 32 + quad * 8);
  }

  f32x4 oaccT[4][2];                 // O^T tiles: [dn][qn], row=d, col=q
  f32x4 laccT[2];                    // l via ones-MFMA (all 4 regs identical)
#pragma unroll
  for (int dn = 0; dn < 4; ++dn)
#pragma unroll
    for (int qn = 0; qn < 2; ++qn) oaccT[dn][qn] = (f32x4){0.f, 0.f, 0.f, 0.f};
#pragma unroll
  for (int qn = 0; qn < 2; ++qn) laccT[qn] = (f32x4){0.f, 0.f, 0.f, 0.f};
  bf16x4 ones4;
#pragma unroll
  for (int i = 0; i < 4; ++i) ones4[i] = (short)0x3F80;  // bf16 1.0

  const int pswz = ((l16 >> 2) & 3) << 3;          // V read-side swizzle key

  uint4 kreg0, kreg1;
  union { uint2 u; u16t hw[4]; } vreg[4];

#define LOAD_TILE(KV0)                                                        \
  do {                                                                        \
    kreg0 = *(const uint4*)(Kbase + (size_t)((KV0) + krow) * C3 + kcol);      \
    kreg1 = *(const uint4*)(Kbase + (size_t)((KV0) + krow + 32) * C3 + kcol); \
    _Pragma("unroll")                                                         \
    for (int i = 0; i < 4; ++i)                                               \
      vreg[i].u = *(const uint2*)(Vbase + (size_t)((KV0) + vk0 + i) * C3 + vd0); \
  } while (0)

#define STORE_TILE()                                                          \
  do {                                                                        \
    *(uint4*)&lK[krow * KSTR + kcol] = kreg0;                                 \
    *(uint4*)&lK[(krow + 32) * KSTR + kcol] = kreg1;                          \
    _Pragma("unroll")                                                         \
    for (int j = 0; j < 4; ++j) {                                             \
      union { uint2 u; u16t hw[4]; } w;                                       \
      w.hw[0] = vreg[0].hw[j]; w.hw[1] = vreg[1].hw[j];                       \
      w.hw[2] = vreg[2].hw[j]; w.hw[3] = vreg[3].hw[j];                       \
      *(uint2*)&lVt[(vd0 + j) * VSTR + (vk0 ^ vswz)] = w.u;                   \
    }                                                                         \
  } while (0)

  LOAD_TILE(kv_begin);
  STORE_TILE();

  for (int kv0 = kv_begin; kv0 < kv_stop; kv0 += 64) {
    const bool havenext = (kv0 + 64 < kv_stop);
    if (havenext) LOAD_TILE(kv0 + 64);   // stays in flight across compute
    BARRIER_LGKM();

    if (kv0 <= wr + 31) {                // wave-uniform skip of masked tiles
      // ---- S^T = K · Q^T (Q pre-scaled; exp2 arg is ready) ----
      f32x4 sacc[4][2];                  // [kvt][qn]
#pragma unroll
      for (int kvt = 0; kvt < 4; ++kvt) {
        bf16x8 kf0 = *(const bf16x8*)&lK[(kvt * 16 + l16) * KSTR + quad * 8];
        bf16x8 kf1 = *(const bf16x8*)&lK[(kvt * 16 + l16) * KSTR + 32 + quad * 8];
#pragma unroll
        for (int qn = 0; qn < 2; ++qn) {
          f32x4 s = (f32x4){0.f, 0.f, 0.f, 0.f};
          s = __builtin_amdgcn_mfma_f32_16x16x32_bf16(kf0, qf[qn][0], s, 0, 0, 0);
          s = __builtin_amdgcn_mfma_f32_16x16x32_bf16(kf1, qf[qn][1], s, 0, 0, 0);
          sacc[kvt][qn] = s;
        }
      }
      const bool need_mask = (kv0 + 63 > wr);
      // ---- P^T = exp2(S^T) -> packed bf16 B-operand registers ----
      bf16x4 pbf[4][2];
#pragma unroll
      for (int kvt = 0; kvt < 4; ++kvt)
#pragma unroll
        for (int qn = 0; qn < 2; ++qn) {
          const int qg = wr + qn * 16 + l16;
          float pv[4];
#pragma unroll
          for (int r = 0; r < 4; ++r) {
            const int kvg = kv0 + kvt * 16 + quad * 4 + r;
            float p = __builtin_amdgcn_exp2f(sacc[kvt][qn][r]);
            if (need_mask && (kvg > qg)) p = 0.f;
            pv[r] = p;
          }
          union { bf16x4 v; unsigned u[2]; } pw;
          pw.u[0] = pk2bf(pv[0], pv[1]);
          pw.u[1] = pk2bf(pv[2], pv[3]);
          pbf[kvt][qn] = pw.v;
        }
      // ---- O^T += V^T · P^T ; l += ones · P^T (both pure MFMA) ----
#pragma unroll
      for (int kvt = 0; kvt < 4; ++kvt) {
        const int kvcol = (kvt * 16 + quad * 4) ^ pswz;
#pragma unroll
        for (int qn = 0; qn < 2; ++qn)
          laccT[qn] = __builtin_amdgcn_mfma_f32_16x16x16bf16_1k(
              ones4, pbf[kvt][qn], laccT[qn], 0, 0, 0);
#pragma unroll
        for (int dn = 0; dn < 4; ++dn) {
          bf16x4 vf = *(const bf16x4*)&lVt[(dn * 16 + l16) * VSTR + kvcol];
#pragma unroll
          for (int qn = 0; qn < 2; ++qn)
            oaccT[dn][qn] = __builtin_amdgcn_mfma_f32_16x16x16bf16_1k(
                vf, pbf[kvt][qn], oaccT[dn][qn], 0, 0, 0);
        }
      }
    }
    BARRIER_LGKM();                      // all reads of LDS tile kv0 done
    if (havenext) STORE_TILE();
  }

  // ---- epilogue: O^T -> [q][d] via per-wave LDS transpose; packed converts.
  {
    u16t* scr = &lVt[wid * 16 * 80];     // 16 q-rows x stride 80 per wave
    u16t* po = pO + ((size_t)h * SLOTS + slot) * 128 * HD;
    float* pl = pL + ((size_t)h * SLOTS + slot) * 128;
#pragma unroll
    for (int qn = 0; qn < 2; ++qn) {
#pragma unroll
      for (int dn = 0; dn < 4; ++dn) {
        union { bf16x4 v; unsigned u[2]; } w;
        w.u[0] = pk2bf(oaccT[dn][qn][0], oaccT[dn][qn][1]);
        w.u[1] = pk2bf(oaccT[dn][qn][2], oaccT[dn][qn][3]);
        *(bf16x4*)&scr[l16 * 80 + dn * 16 + quad * 4] = w.v;
      }
      __asm__ __volatile__("s_waitcnt lgkmcnt(0)" ::: "memory");
      const int ql = wid * 32 + qn * 16 + l16;
      uint4 w0 = *(const uint4*)&scr[l16 * 80 + quad * 16];
      uint4 w1 = *(const uint4*)&scr[l16 * 80 + quad * 16 + 8];
      u16t* dst = po + (size_t)ql * HD + quad * 16;
      *(uint4*)dst = w0;
      *(uint4*)(dst + 8) = w1;
      if (quad == 0) pl[ql] = laccT[qn][0];
      __asm__ __volatile__("s_waitcnt lgkmcnt(0)" ::: "memory");
    }
  }
#undef LOAD_TILE
#undef STORE_TILE
}

// ---------------------------------------------------------------------------
// 8-wide: each thread normalizes 8 consecutive d of one (q,h).
// ---------------------------------------------------------------------------
__global__ __launch_bounds__(256) void attn_normalize(const u16t* __restrict__ pO,
                                                      const float* __restrict__ pL,
                                                      u16t* __restrict__ y) {
  const int i = blockIdx.x * 256 + threadIdx.x;   // over T*C/8
  const int q = i / (CDIM / 8), c8 = (i % (CDIM / 8)) * 8;
  const int h = c8 >> 6, d = c8 & 63;
  const int qt = q >> 7, ql = q & 127;
  const int a = qt >> 2, b = qt & 3;
  const int base = (a + 1) * (2 * a + b);
  const int ns = a + 1;                            // ceil((qt+1)/4)
  float o[8] = {0.f, 0.f, 0.f, 0.f, 0.f, 0.f, 0.f, 0.f};
  float l = 0.f;
  for (int s = 0; s < ns; ++s) {
    const size_t sl = (size_t)h * SLOTS + base + s;
    union { uint4 u; u16t hw[8]; } v;
    v.u = *(const uint4*)&pO[(sl * 128 + ql) * HD + d];
#pragma unroll
    for (int j = 0; j < 8; ++j) o[j] += bf2f(v.hw[j]);
    l += pL[sl * 128 + ql];
  }
  const float rl = 1.0f / l;
  union { uint4 u; unsigned w[4]; } wv;
#pragma unroll
  for (int j = 0; j < 4; ++j)
    wv.w[j] = pk2bf(o[2 * j] * rl, o[2 * j + 1] * rl);
  *(uint4*)&y[(size_t)q * CDIM + c8] = wv.u;
}

// ---------------------------------------------------------------------------
extern "C" void kernel_launch(void* const* d_in, const int* in_sizes, int n_in,
                              void* d_out, int out_size, void* d_ws, size_t ws_size,
                              hipStream_t stream) {
  const float* x     = (const float*)d_in[0];
  // d_in[1] = mask (unused — causal mask applied analytically)
  const float* Wqkv  = (const float*)d_in[2];
  const float* bqkv  = (const float*)d_in[3];
  const float* Wproj = (const float*)d_in[4];
  const float* bproj = (const float*)d_in[5];

  u16t* qkv    = (u16t*)d_ws;                     // [4096][2304] bf16
  u16t* ybuf   = qkv    + (size_t)T_SEQ * C3;     // [4096][768]  bf16 (x, then attn out)
  u16t* WqkvT  = ybuf   + (size_t)T_SEQ * CDIM;   // [2304][768]  bf16
  u16t* WprojT = WqkvT  + (size_t)C3 * CDIM;      // [768][768]   bf16
  u16t* pO     = WprojT + (size_t)CDIM * CDIM;    // [12][144][128][64] bf16
  float* pL    = (float*)(pO + (size_t)NH * SLOTS * 128 * HD);  // [12][144][128] f32

  convert_to_bf16<<<1024, 256, 0, stream>>>(x, ybuf, T_SEQ * CDIM);
  transpose_weights<<<dim3(C3 / 32, CDIM / 32, 2), dim3(32, 8), 0, stream>>>(
      Wqkv, Wproj, WqkvT, WprojT);
  gemm_bt_bias<128, 4, false><<<dim3(C3 / 128, T_SEQ / 128), 256, 0, stream>>>(
      ybuf, WqkvT, bqkv, qkv, T_SEQ, C3, CDIM, CDIM, SC_F);
  attn_partial<<<dim3(NH, 8, T_SEQ / 128), 256, 0, stream>>>(qkv, pO, pL);
  attn_normalize<<<(T_SEQ * CDIM / 8) / 256, 256, 0, stream>>>(pO, pL, ybuf);
  gemm_bt_bias<64, 2, true><<<dim3(CDIM / 64, T_SEQ / 64), 256, 0, stream>>>(
      ybuf, WprojT, bproj, d_out, T_SEQ, CDIM, CDIM, 0, 1.0f);
}